// Round 19
// baseline (145.832 us; speedup 1.0000x reference)
//
#include <hip/hip_runtime.h>
#include <hip/hip_fp16.h>

#define NN 100000
#define NE 1600000

// Radix partition params: buckets of 256 nodes
#define K_B 391                          // ceil(NN/256) buckets
#define B_P 1000                         // partition blocks (~4/CU for TLP)
#define CH  1600                         // edges per partition block (4-aligned)
#define CH4 (CH / 4)                     // 4-edge chunks per block (400)
#define NSC (K_B * B_P)                  // histogram table size (391000)
#define SC_CHUNK 4096                    // elems per gscan1 block
#define SC_SH 12                         // log2(SC_CHUNK)
#define NBLK_H ((NSC + SC_CHUNK - 1) / SC_CHUNK)   // 96 blocks (<=128)
#define ITER_B 20                        // max cached edges/thread in k_bucket

// ---------------------------------------------------------------------------
// Per-block edge dtype self-detection: odd 32-bit words of int64 data (values
// < 2^31) are all zero; for int32 data they are random src values (each zero
// with p=1e-5; 16 in a row all-zero: p=1e-80). No separate kernel needed.
__device__ __forceinline__ int detect_is32(const void* ei, int e0) {
    const unsigned* w = (const unsigned*)ei;
    unsigned acc = 0;
#pragma unroll
    for (int u = 0; u < 16; ++u) acc |= w[2 * (e0 + u) + 1];
    return acc != 0u;
}

// ---------------------------------------------------------------------------
// P1: per-block histogram of dst>>8 (vectorized: 4 edges per thread-iter)
__global__ __launch_bounds__(256) void k_hist(const void* ei, int* __restrict__ hist) {
    __shared__ int h[K_B];
    for (int i = threadIdx.x; i < K_B; i += 256) h[i] = 0;
    __syncthreads();
    int b = blockIdx.x;
    int is32 = detect_is32(ei, b * CH);
    for (int c = threadIdx.x; c < CH4; c += 256) {
        int e = (b * CH4 + c) * 4;
        int d0, d1, d2, d3;
        if (is32) {
            int4 d4 = *(const int4*)((const int*)ei + NE + e);
            d0 = d4.x; d1 = d4.y; d2 = d4.z; d3 = d4.w;
        } else {
            const long long* p = (const long long*)ei + NE + e;
            d0 = (int)p[0]; d1 = (int)p[1]; d2 = (int)p[2]; d3 = (int)p[3];
        }
        atomicAdd(&h[d0 >> 8], 1);
        atomicAdd(&h[d1 >> 8], 1);
        atomicAdd(&h[d2 >> 8], 1);
        atomicAdd(&h[d3 >> 8], 1);
    }
    __syncthreads();
    for (int i = threadIdx.x; i < K_B; i += 256) hist[i * B_P + b] = h[i];
}

// ---------------------------------------------------------------------------
// Hierarchical exclusive scan: 1024-thread blocks, 4 elems/thread (4096/blk)
__global__ __launch_bounds__(1024) void k_gscan1(const int* __restrict__ in,
                                                 int* __restrict__ ex,
                                                 int* __restrict__ bsum, int n) {
    __shared__ int lds[1024];
    int b = blockIdx.x, t = threadIdx.x;
    int base = b * SC_CHUNK + t * 4;
    int v[4];
#pragma unroll
    for (int k = 0; k < 4; ++k) { int i = base + k; v[k] = (i < n) ? in[i] : 0; }
    int s = v[0] + v[1] + v[2] + v[3];
    lds[t] = s;
    __syncthreads();
    for (int off = 1; off < 1024; off <<= 1) {
        int tmp = (t >= off) ? lds[t - off] : 0;
        __syncthreads();
        lds[t] += tmp;
        __syncthreads();
    }
    int run = lds[t] - s;
#pragma unroll
    for (int k = 0; k < 4; ++k) {
        int i = base + k;
        if (i < n) ex[i] = run;
        run += v[k];
    }
    if (t == 1023) bsum[b] = lds[1023];
}

__global__ __launch_bounds__(128) void k_gscan2(int* bsum, int nblk) {
    __shared__ int lds[128];
    int t = threadIdx.x;
    int v = (t < nblk) ? bsum[t] : 0;
    lds[t] = v;
    __syncthreads();
    for (int off = 1; off < 128; off <<= 1) {
        int tmp = (t >= off) ? lds[t - off] : 0;
        __syncthreads();
        lds[t] += tmp;
        __syncthreads();
    }
    if (t < nblk) bsum[t] = lds[t] - v;  // exclusive
}

// ---------------------------------------------------------------------------
// P3: partition edges into per-(block,bucket) runs (LDS cursors, 4 edges/iter)
// off(idx) = ex[idx] + bsum[idx>>SC_SH]   (gscan3 folded in)
__global__ __launch_bounds__(256) void k_part(const void* ei,
                                              const int* __restrict__ ex,
                                              const int* __restrict__ bsum,
                                              unsigned* __restrict__ packed) {
    __shared__ int cur[K_B];
    int b = blockIdx.x;
    for (int i = threadIdx.x; i < K_B; i += 256) {
        int idx = i * B_P + b;
        cur[i] = ex[idx] + bsum[idx >> SC_SH];
    }
    __syncthreads();
    int is32 = detect_is32(ei, b * CH);
    for (int c = threadIdx.x; c < CH4; c += 256) {
        int e = (b * CH4 + c) * 4;
        int s[4], d[4];
        if (is32) {
            int4 s4 = *(const int4*)((const int*)ei + e);
            int4 d4 = *(const int4*)((const int*)ei + NE + e);
            s[0] = s4.x; s[1] = s4.y; s[2] = s4.z; s[3] = s4.w;
            d[0] = d4.x; d[1] = d4.y; d[2] = d4.z; d[3] = d4.w;
        } else {
            const long long* ps = (const long long*)ei + e;
            const long long* pd = (const long long*)ei + NE + e;
#pragma unroll
            for (int u = 0; u < 4; ++u) { s[u] = (int)ps[u]; d[u] = (int)pd[u]; }
        }
#pragma unroll
        for (int u = 0; u < 4; ++u) {
            int k = d[u] >> 8;
            int pos = atomicAdd(&cur[k], 1);
            packed[pos] = ((unsigned)s[u] << 8) | (unsigned)(d[u] & 255);
        }
    }
}

// ---------------------------------------------------------------------------
// P4 fused per-bucket, SINGLE PASS over packed: count with rank cached in
// registers (rank in bits [25,31) of the cached word; src<2^17 so pk<2^25),
// local scan -> rowptr/dinv/xn, then place ssrc from the register cache.
// Overflow (bucket>5120 edges or node deg>127 — p~0 for Poisson(16)) drains
// through a small LDS buffer for correctness.
__global__ __launch_bounds__(256) void k_bucket(const int* __restrict__ ex,
                                                const int* __restrict__ bsum,
                                                const unsigned* __restrict__ packed,
                                                const float* __restrict__ x,
                                                int* __restrict__ rowptr,
                                                float* __restrict__ dinv,
                                                float2* __restrict__ xn,
                                                int* __restrict__ ssrc) {
    __shared__ int cnt[256];
    __shared__ int excl[256];
    __shared__ int ovf_n;
    __shared__ unsigned ovf_pk[256];
    __shared__ int ovf_rk[256];
    int k = blockIdx.x, t = threadIdx.x;
    cnt[t] = 0;
    if (t == 0) ovf_n = 0;
    __syncthreads();
    int i0 = k * B_P;
    int g0 = ex[i0] + bsum[i0 >> SC_SH];
    int g1 = NE;
    if (k != K_B - 1) { int i1 = i0 + B_P; g1 = ex[i1] + bsum[i1 >> SC_SH]; }
    unsigned pkv[ITER_B];
#pragma unroll
    for (int it = 0; it < ITER_B; ++it) {
        int i = g0 + it * 256 + t;
        unsigned pk = 0xFFFFFFFFu;
        if (i < g1) {
            pk = packed[i];
            int r = atomicAdd(&cnt[pk & 255u], 1);
            if (r < 127) {
                pk |= (unsigned)r << 25;
            } else {                       // statistically never
                int o = atomicAdd(&ovf_n, 1);
                ovf_pk[o & 255] = pk; ovf_rk[o & 255] = r;
                pk = 0xFFFFFFFFu;
            }
        }
        pkv[it] = pk;
    }
    for (int i = g0 + ITER_B * 256 + t; i < g1; i += 256) {  // never executes
        unsigned pk = packed[i];
        int r = atomicAdd(&cnt[pk & 255u], 1);
        int o = atomicAdd(&ovf_n, 1);
        ovf_pk[o & 255] = pk; ovf_rk[o & 255] = r;
    }
    __syncthreads();
    int v = cnt[t];
    excl[t] = v;
    __syncthreads();
    for (int o = 1; o < 256; o <<= 1) {
        int tmp = (t >= o) ? excl[t - o] : 0;
        __syncthreads();
        excl[t] += tmp;
        __syncthreads();
    }
    // excl[t] = inclusive prefix; node row base = g0 + excl[dl] - cnt[dl]
    int rb = g0 + excl[t] - v;
    int n = (k << 8) + t;
    if (n < NN) {
        rowptr[n] = rb;
        float di = rsqrtf((float)(v + 1));  // +1 self-loop
        dinv[n] = di;
        float2 xv = ((const float2*)x)[n];
        xn[n] = make_float2(xv.x * di, xv.y * di);
    }
    if (k == K_B - 1 && t == 0) rowptr[NN] = NE;
    // place from register cache (excl/cnt stable; no further barrier needed)
#pragma unroll
    for (int it = 0; it < ITER_B; ++it) {
        unsigned pk = pkv[it];
        if (pk != 0xFFFFFFFFu) {
            int dl = pk & 255u;
            int r  = (int)(pk >> 25);
            int sv = (int)((pk >> 8) & 0x1FFFFu);
            ssrc[g0 + excl[dl] - cnt[dl] + r] = sv;
        }
    }
    for (int o = t; o < ovf_n; o += 256) {   // never executes
        unsigned pk = ovf_pk[o];
        int dl = pk & 255u;
        ssrc[g0 + excl[dl] - cnt[dl] + ovf_rk[o]] = (int)(pk >> 8) & 0x1FFFF;
    }
}

// ---------------------------------------------------------------------------
// Layer 1 + W2 fused: 4 nodes/wave 16-lane gather of xn, then per node the
// 2->64 transform (lane = feature) AND the 64x64 W2 matvec in-wave via
// readlane (W2 column in 64 VGPRs). tn1[n][l] = fp16( (hn1[n] @ W2)_l )
__global__ __launch_bounds__(256) void k_layer1(const int* __restrict__ rowptr,
                                                const int* __restrict__ ssrc,
                                                const float2* __restrict__ xn,
                                                const float* __restrict__ dinv,
                                                const float* __restrict__ W1,
                                                const float* __restrict__ b1,
                                                const float* __restrict__ W2,
                                                __half* __restrict__ tn1) {
    int w = threadIdx.x >> 6, lane = threadIdx.x & 63;
    float wc[64];
#pragma unroll
    for (int j = 0; j < 64; ++j) wc[j] = W2[j * 64 + lane];  // W2 column 'lane'
    float w1a = W1[lane], w1b = W1[64 + lane], bb = b1[lane];
    int grp = lane >> 4, sub = lane & 15;
    int nbase = blockIdx.x * 16 + w * 4;      // grid exact: 6250*16 = NN
    int node = nbase + grp;
    int s0 = rowptr[node], e0 = rowptr[node + 1];
    float ax = 0.f, ay = 0.f;
    for (int i = s0 + sub; i < e0; i += 16) {
        float2 v = xn[ssrc[i]];
        ax += v.x; ay += v.y;
    }
#pragma unroll
    for (int m = 1; m < 16; m <<= 1) {        // reduce within 16-lane group
        ax += __shfl_xor(ax, m, 64);
        ay += __shfl_xor(ay, m, 64);
    }
#pragma unroll
    for (int c = 0; c < 4; ++c) {             // 4 per-node epilogues
        float axc = __shfl(ax, c * 16, 64);
        float ayc = __shfl(ay, c * 16, 64);
        int nc = nbase + c;
        float2 a = xn[nc];                    // self loop
        float di = dinv[nc];
        float axn = (axc + a.x) * di;
        float ayn = (ayc + a.y) * di;
        float h = di * fmaxf(fmaf(axn, w1a, fmaf(ayn, w1b, bb)), 0.f);
        float t = 0.f;
#pragma unroll
        for (int j = 0; j < 64; ++j) {        // in-wave 64x64 matvec
            float hj = __uint_as_float(__builtin_amdgcn_readlane(__float_as_uint(h), j));
            t = fmaf(hj, wc[j], t);
        }
        tn1[(size_t)nc * 64 + lane] = __float2half(t);
    }
}

// ---------------------------------------------------------------------------
// Layer 2+3a aggregate, 2 nodes per wave with a COMBINED edge list, unroll 8
// (measured sweet spot: unroll 4 = 61us, 8 = 53.5us, 16 = 64us). Tail is one
// PREDICATED unroll-8 block: all <=7 tail loads issue in parallel under
// wave-uniform guards instead of one-at-a-time. All-register epilogue.
__global__ __launch_bounds__(256) void k_layer2agg(const int* __restrict__ rowptr,
                                                   const int* __restrict__ ssrc,
                                                   const __half* __restrict__ tn1,
                                                   const float* __restrict__ dinv,
                                                   const float* __restrict__ b2,
                                                   const float* __restrict__ W3,
                                                   float* __restrict__ t3) {
    int w = threadIdx.x >> 6, lane = threadIdx.x & 63;
    int n0 = blockIdx.x * 8 + w * 2;          // grid exact: 12500*8 = NN
    int n1 = n0 + 1;
    int s0 = rowptr[n0], e0 = rowptr[n0 + 1], e1 = rowptr[n0 + 2];
    int d0 = e0 - s0, tot = e1 - s0;          // combined d0 + d1 edges
    float a0 = __half2float(tn1[(size_t)n0 * 64 + lane]);  // self loops
    float a1 = __half2float(tn1[(size_t)n1 * 64 + lane]);
    int j = 0;
    for (; j + 8 <= tot; j += 8) {
#pragma unroll
        for (int u = 0; u < 8; ++u) {
            int jj = j + u;                   // wave-uniform slot
            float v = __half2float(tn1[(size_t)ssrc[s0 + jj] * 64 + lane]);
            if (jj < d0) a0 += v; else a1 += v;   // uniform branch
        }
    }
#pragma unroll
    for (int u = 0; u < 8; ++u) {             // predicated parallel tail
        int jj = j + u;
        if (jj < tot) {
            float v = __half2float(tn1[(size_t)ssrc[s0 + jj] * 64 + lane]);
            if (jj < d0) a0 += v; else a1 += v;
        }
    }
    float w3 = W3[lane], bb = b2[lane];
    float di0 = dinv[n0];
    float r0 = di0 * fmaxf(fmaf(di0, a0, bb), 0.f) * w3;
    float di1 = dinv[n1];
    float r1 = di1 * fmaxf(fmaf(di1, a1, bb), 0.f) * w3;
#pragma unroll
    for (int m = 1; m < 64; m <<= 1) {
        r0 += __shfl_xor(r0, m, 64);
        r1 += __shfl_xor(r1, m, 64);
    }
    if (lane == 0) { t3[n0] = r0; t3[n1] = r1; }
}

// Scalar last layer: out[n] = dinv[n]*(t3[n] + sum t3[src]) + b3
__global__ void k_aggregate3(const int* __restrict__ rowptr, const int* __restrict__ ssrc,
                             const float* __restrict__ t3, const float* __restrict__ dinv,
                             const float* __restrict__ b3, float* __restrict__ out) {
    int n = blockIdx.x * blockDim.x + threadIdx.x;
    if (n >= NN) return;
    int s = rowptr[n], e = rowptr[n + 1];
    float acc = t3[n];
    int i = s;
    for (; i + 8 <= e; i += 8) {
        float v0 = t3[ssrc[i]]     + t3[ssrc[i + 1]];
        float v1 = t3[ssrc[i + 2]] + t3[ssrc[i + 3]];
        float v2 = t3[ssrc[i + 4]] + t3[ssrc[i + 5]];
        float v3 = t3[ssrc[i + 6]] + t3[ssrc[i + 7]];
        acc += (v0 + v1) + (v2 + v3);
    }
    for (; i < e; ++i) acc += t3[ssrc[i]];
    out[n] = dinv[n] * acc + b3[0];
}

// ---------------------------------------------------------------------------
extern "C" void kernel_launch(void* const* d_in, const int* in_sizes, int n_in,
                              void* d_out, int out_size, void* d_ws, size_t ws_size,
                              hipStream_t stream) {
    const float* x  = (const float*)d_in[0];
    const void*  ei = d_in[1];
    const float* W1 = (const float*)d_in[2];
    const float* b1 = (const float*)d_in[3];
    const float* W2 = (const float*)d_in[4];
    const float* b2 = (const float*)d_in[5];
    const float* W3 = (const float*)d_in[6];
    const float* b3 = (const float*)d_in[7];
    float* out = (float*)d_out;

    char* ws = (char*)d_ws;
    size_t off_b = 0;
    auto take = [&](size_t bytes) -> char* {
        char* p = ws + off_b;
        off_b = (off_b + bytes + 255) & ~(size_t)255;
        return p;
    };
    float*    dinv   = (float*)take((size_t)NN * 4);
    int*      bsum   = (int*)take(128 * 4);
    int*      rowptr = (int*)take((size_t)(NN + 1) * 4);
    int*      hist   = (int*)take((size_t)NSC * 4);
    int*      histS  = (int*)take((size_t)NSC * 4);
    unsigned* packed = (unsigned*)take((size_t)NE * 4);
    int*      ssrc   = (int*)take((size_t)NE * 4);
    float2*   xn     = (float2*)take((size_t)NN * 8);
    __half*   tn1    = (__half*)take((size_t)NN * 64 * 2);
    float*    t3     = (float*)take((size_t)NN * 4);

    // --- atomic-free radix partition by dst (coarse buckets of 256 nodes) ---
    k_hist<<<B_P, 256, 0, stream>>>(ei, hist);
    k_gscan1<<<NBLK_H, 1024, 0, stream>>>(hist, histS, bsum, NSC);
    k_gscan2<<<1, 128, 0, stream>>>(bsum, NBLK_H);
    k_part<<<B_P, 256, 0, stream>>>(ei, histS, bsum, packed);

    // --- fused per-bucket: count + scan -> rowptr/dinv/xn + place ssrc ---
    k_bucket<<<K_B, 256, 0, stream>>>(histS, bsum, packed, x, rowptr, dinv, xn, ssrc);

    // --- layer 1 + W2 (4 nodes/wave gather, in-wave 64x64 matvec, fp16 out) ---
    k_layer1<<<(NN + 15) / 16, 256, 0, stream>>>(rowptr, ssrc, xn, dinv, W1, b1, W2, tn1);

    // --- layer 2 aggregate (2 nodes/wave, unroll 8) + epilogue + W3 dot ---
    k_layer2agg<<<(NN + 7) / 8, 256, 0, stream>>>(rowptr, ssrc, tn1, dinv, b2, W3, t3);

    // --- layer 3b (scalar aggregate) ---
    k_aggregate3<<<(NN + 255) / 256, 256, 0, stream>>>(rowptr, ssrc, t3, dinv, b3, out);
}

// Round 20
// 138.416 us; speedup vs baseline: 1.0536x; 1.0536x over previous
//
#include <hip/hip_runtime.h>
#include <hip/hip_fp16.h>

#define NN 100000
#define NE 1600000

// Radix partition params: buckets of 256 nodes
#define K_B 391                          // ceil(NN/256) buckets
#define B_P 250                          // partition blocks
#define CH  6400                         // edges per partition block (4-aligned)
#define CH4 (CH / 4)                     // 4-edge chunks per block
#define NSC (K_B * B_P)                  // histogram table size (97750)
#define NBLK_H ((NSC + 1023) / 1024)     // blocks for hist scan (96)
#define ITER_B 20                        // max cached edges/thread in k_bucket

// ---------------------------------------------------------------------------
// Per-block edge dtype self-detection: odd 32-bit words of int64 data (values
// < 2^31) are all zero; for int32 data they are random src values (each zero
// with p=1e-5; 16 in a row all-zero: p=1e-80). No separate kernel needed.
__device__ __forceinline__ int detect_is32(const void* ei, int e0) {
    const unsigned* w = (const unsigned*)ei;
    unsigned acc = 0;
#pragma unroll
    for (int u = 0; u < 16; ++u) acc |= w[2 * (e0 + u) + 1];
    return acc != 0u;
}

// ---------------------------------------------------------------------------
// P1: per-block histogram of dst>>8 (vectorized: 4 edges per thread-iter)
__global__ __launch_bounds__(256) void k_hist(const void* ei, int* __restrict__ hist) {
    __shared__ int h[K_B];
    for (int i = threadIdx.x; i < K_B; i += 256) h[i] = 0;
    __syncthreads();
    int b = blockIdx.x;
    int is32 = detect_is32(ei, b * CH);
    for (int c = threadIdx.x; c < CH4; c += 256) {
        int e = (b * CH4 + c) * 4;
        int d0, d1, d2, d3;
        if (is32) {
            int4 d4 = *(const int4*)((const int*)ei + NE + e);
            d0 = d4.x; d1 = d4.y; d2 = d4.z; d3 = d4.w;
        } else {
            const long long* p = (const long long*)ei + NE + e;
            d0 = (int)p[0]; d1 = (int)p[1]; d2 = (int)p[2]; d3 = (int)p[3];
        }
        atomicAdd(&h[d0 >> 8], 1);
        atomicAdd(&h[d1 >> 8], 1);
        atomicAdd(&h[d2 >> 8], 1);
        atomicAdd(&h[d3 >> 8], 1);
    }
    __syncthreads();
    for (int i = threadIdx.x; i < K_B; i += 256) hist[i * B_P + b] = h[i];
}

// ---------------------------------------------------------------------------
// Hierarchical exclusive scan, kernels 1+2 (k3 folded into consumers)
__global__ __launch_bounds__(256) void k_gscan1(const int* __restrict__ in,
                                                int* __restrict__ ex,
                                                int* __restrict__ bsum, int n) {
    __shared__ int lds[256];
    int b = blockIdx.x, t = threadIdx.x;
    int base = b * 1024 + t * 4;
    int v[4];
#pragma unroll
    for (int k = 0; k < 4; ++k) { int i = base + k; v[k] = (i < n) ? in[i] : 0; }
    int s = v[0] + v[1] + v[2] + v[3];
    lds[t] = s;
    __syncthreads();
    for (int off = 1; off < 256; off <<= 1) {
        int tmp = (t >= off) ? lds[t - off] : 0;
        __syncthreads();
        lds[t] += tmp;
        __syncthreads();
    }
    int run = lds[t] - s;
#pragma unroll
    for (int k = 0; k < 4; ++k) {
        int i = base + k;
        if (i < n) ex[i] = run;
        run += v[k];
    }
    if (t == 255) bsum[b] = lds[255];
}

__global__ __launch_bounds__(128) void k_gscan2(int* bsum, int nblk) {
    __shared__ int lds[128];
    int t = threadIdx.x;
    int v = (t < nblk) ? bsum[t] : 0;
    lds[t] = v;
    __syncthreads();
    for (int off = 1; off < 128; off <<= 1) {
        int tmp = (t >= off) ? lds[t - off] : 0;
        __syncthreads();
        lds[t] += tmp;
        __syncthreads();
    }
    if (t < nblk) bsum[t] = lds[t] - v;  // exclusive
}

// ---------------------------------------------------------------------------
// P3: partition edges into per-(block,bucket) runs (LDS cursors, 4 edges/iter)
// off(idx) = ex[idx] + bsum[idx>>10]   (gscan3 folded in)
__global__ __launch_bounds__(256) void k_part(const void* ei,
                                              const int* __restrict__ ex,
                                              const int* __restrict__ bsum,
                                              unsigned* __restrict__ packed) {
    __shared__ int cur[K_B];
    int b = blockIdx.x;
    for (int i = threadIdx.x; i < K_B; i += 256) {
        int idx = i * B_P + b;
        cur[i] = ex[idx] + bsum[idx >> 10];
    }
    __syncthreads();
    int is32 = detect_is32(ei, b * CH);
    for (int c = threadIdx.x; c < CH4; c += 256) {
        int e = (b * CH4 + c) * 4;
        int s[4], d[4];
        if (is32) {
            int4 s4 = *(const int4*)((const int*)ei + e);
            int4 d4 = *(const int4*)((const int*)ei + NE + e);
            s[0] = s4.x; s[1] = s4.y; s[2] = s4.z; s[3] = s4.w;
            d[0] = d4.x; d[1] = d4.y; d[2] = d4.z; d[3] = d4.w;
        } else {
            const long long* ps = (const long long*)ei + e;
            const long long* pd = (const long long*)ei + NE + e;
#pragma unroll
            for (int u = 0; u < 4; ++u) { s[u] = (int)ps[u]; d[u] = (int)pd[u]; }
        }
#pragma unroll
        for (int u = 0; u < 4; ++u) {
            int k = d[u] >> 8;
            int pos = atomicAdd(&cur[k], 1);
            packed[pos] = ((unsigned)s[u] << 8) | (unsigned)(d[u] & 255);
        }
    }
}

// ---------------------------------------------------------------------------
// P4 fused per-bucket, SINGLE PASS over packed: count with rank cached in
// registers (rank in bits [25,31) of the cached word; src<2^17 so pk<2^25),
// local scan -> rowptr/dinv/xn, then place ssrc from the register cache.
// Overflow (bucket>5120 edges or node deg>127 — p~0 for Poisson(16)) drains
// through a small LDS buffer for correctness.
__global__ __launch_bounds__(256) void k_bucket(const int* __restrict__ ex,
                                                const int* __restrict__ bsum,
                                                const unsigned* __restrict__ packed,
                                                const float* __restrict__ x,
                                                int* __restrict__ rowptr,
                                                float* __restrict__ dinv,
                                                float2* __restrict__ xn,
                                                int* __restrict__ ssrc) {
    __shared__ int cnt[256];
    __shared__ int excl[256];
    __shared__ int ovf_n;
    __shared__ unsigned ovf_pk[256];
    __shared__ int ovf_rk[256];
    int k = blockIdx.x, t = threadIdx.x;
    cnt[t] = 0;
    if (t == 0) ovf_n = 0;
    __syncthreads();
    int i0 = k * B_P;
    int g0 = ex[i0] + bsum[i0 >> 10];
    int g1 = NE;
    if (k != K_B - 1) { int i1 = i0 + B_P; g1 = ex[i1] + bsum[i1 >> 10]; }
    unsigned pkv[ITER_B];
#pragma unroll
    for (int it = 0; it < ITER_B; ++it) {
        int i = g0 + it * 256 + t;
        unsigned pk = 0xFFFFFFFFu;
        if (i < g1) {
            pk = packed[i];
            int r = atomicAdd(&cnt[pk & 255u], 1);
            if (r < 127) {
                pk |= (unsigned)r << 25;
            } else {                       // statistically never
                int o = atomicAdd(&ovf_n, 1);
                ovf_pk[o & 255] = pk; ovf_rk[o & 255] = r;
                pk = 0xFFFFFFFFu;
            }
        }
        pkv[it] = pk;
    }
    for (int i = g0 + ITER_B * 256 + t; i < g1; i += 256) {  // never executes
        unsigned pk = packed[i];
        int r = atomicAdd(&cnt[pk & 255u], 1);
        int o = atomicAdd(&ovf_n, 1);
        ovf_pk[o & 255] = pk; ovf_rk[o & 255] = r;
    }
    __syncthreads();
    int v = cnt[t];
    excl[t] = v;
    __syncthreads();
    for (int o = 1; o < 256; o <<= 1) {
        int tmp = (t >= o) ? excl[t - o] : 0;
        __syncthreads();
        excl[t] += tmp;
        __syncthreads();
    }
    // excl[t] = inclusive prefix; node row base = g0 + excl[dl] - cnt[dl]
    int rb = g0 + excl[t] - v;
    int n = (k << 8) + t;
    if (n < NN) {
        rowptr[n] = rb;
        float di = rsqrtf((float)(v + 1));  // +1 self-loop
        dinv[n] = di;
        float2 xv = ((const float2*)x)[n];
        xn[n] = make_float2(xv.x * di, xv.y * di);
    }
    if (k == K_B - 1 && t == 0) rowptr[NN] = NE;
    // place from register cache (excl/cnt stable; no further barrier needed)
#pragma unroll
    for (int it = 0; it < ITER_B; ++it) {
        unsigned pk = pkv[it];
        if (pk != 0xFFFFFFFFu) {
            int dl = pk & 255u;
            int r  = (int)(pk >> 25);
            int sv = (int)((pk >> 8) & 0x1FFFFu);
            ssrc[g0 + excl[dl] - cnt[dl] + r] = sv;
        }
    }
    for (int o = t; o < ovf_n; o += 256) {   // never executes
        unsigned pk = ovf_pk[o];
        int dl = pk & 255u;
        ssrc[g0 + excl[dl] - cnt[dl] + ovf_rk[o]] = (int)(pk >> 8) & 0x1FFFF;
    }
}

// ---------------------------------------------------------------------------
// Layer 1 + W2 fused: 4 nodes/wave 16-lane gather of xn, then per node the
// 2->64 transform (lane = feature) AND the 64x64 W2 matvec in-wave via
// readlane (W2 column in 64 VGPRs). tn1[n][l] = fp16( (hn1[n] @ W2)_l )
__global__ __launch_bounds__(256) void k_layer1(const int* __restrict__ rowptr,
                                                const int* __restrict__ ssrc,
                                                const float2* __restrict__ xn,
                                                const float* __restrict__ dinv,
                                                const float* __restrict__ W1,
                                                const float* __restrict__ b1,
                                                const float* __restrict__ W2,
                                                __half* __restrict__ tn1) {
    int w = threadIdx.x >> 6, lane = threadIdx.x & 63;
    float wc[64];
#pragma unroll
    for (int j = 0; j < 64; ++j) wc[j] = W2[j * 64 + lane];  // W2 column 'lane'
    float w1a = W1[lane], w1b = W1[64 + lane], bb = b1[lane];
    int grp = lane >> 4, sub = lane & 15;
    int nbase = blockIdx.x * 16 + w * 4;      // grid exact: 6250*16 = NN
    int node = nbase + grp;
    int s0 = rowptr[node], e0 = rowptr[node + 1];
    float ax = 0.f, ay = 0.f;
    for (int i = s0 + sub; i < e0; i += 16) {
        float2 v = xn[ssrc[i]];
        ax += v.x; ay += v.y;
    }
#pragma unroll
    for (int m = 1; m < 16; m <<= 1) {        // reduce within 16-lane group
        ax += __shfl_xor(ax, m, 64);
        ay += __shfl_xor(ay, m, 64);
    }
#pragma unroll
    for (int c = 0; c < 4; ++c) {             // 4 per-node epilogues
        float axc = __shfl(ax, c * 16, 64);
        float ayc = __shfl(ay, c * 16, 64);
        int nc = nbase + c;
        float2 a = xn[nc];                    // self loop
        float di = dinv[nc];
        float axn = (axc + a.x) * di;
        float ayn = (ayc + a.y) * di;
        float h = di * fmaxf(fmaf(axn, w1a, fmaf(ayn, w1b, bb)), 0.f);
        float t = 0.f;
#pragma unroll
        for (int j = 0; j < 64; ++j) {        // in-wave 64x64 matvec
            float hj = __uint_as_float(__builtin_amdgcn_readlane(__float_as_uint(h), j));
            t = fmaf(hj, wc[j], t);
        }
        tn1[(size_t)nc * 64 + lane] = __float2half(t);
    }
}

// ---------------------------------------------------------------------------
// Layer 2+3a aggregate, 2 nodes per wave with a COMBINED edge list, unroll 8
// (measured sweet spot: unroll 4 = 61us, 8 = 53.5us, 16 = 64us). Tail is one
// PREDICATED unroll-8 block: all <=7 tail loads issue in parallel under
// wave-uniform guards instead of one-at-a-time. All-register epilogue.
__global__ __launch_bounds__(256) void k_layer2agg(const int* __restrict__ rowptr,
                                                   const int* __restrict__ ssrc,
                                                   const __half* __restrict__ tn1,
                                                   const float* __restrict__ dinv,
                                                   const float* __restrict__ b2,
                                                   const float* __restrict__ W3,
                                                   float* __restrict__ t3) {
    int w = threadIdx.x >> 6, lane = threadIdx.x & 63;
    int n0 = blockIdx.x * 8 + w * 2;          // grid exact: 12500*8 = NN
    int n1 = n0 + 1;
    int s0 = rowptr[n0], e0 = rowptr[n0 + 1], e1 = rowptr[n0 + 2];
    int d0 = e0 - s0, tot = e1 - s0;          // combined d0 + d1 edges
    float a0 = __half2float(tn1[(size_t)n0 * 64 + lane]);  // self loops
    float a1 = __half2float(tn1[(size_t)n1 * 64 + lane]);
    int j = 0;
    for (; j + 8 <= tot; j += 8) {
#pragma unroll
        for (int u = 0; u < 8; ++u) {
            int jj = j + u;                   // wave-uniform slot
            float v = __half2float(tn1[(size_t)ssrc[s0 + jj] * 64 + lane]);
            if (jj < d0) a0 += v; else a1 += v;   // uniform branch
        }
    }
#pragma unroll
    for (int u = 0; u < 8; ++u) {             // predicated parallel tail
        int jj = j + u;
        if (jj < tot) {
            float v = __half2float(tn1[(size_t)ssrc[s0 + jj] * 64 + lane]);
            if (jj < d0) a0 += v; else a1 += v;
        }
    }
    float w3 = W3[lane], bb = b2[lane];
    float di0 = dinv[n0];
    float r0 = di0 * fmaxf(fmaf(di0, a0, bb), 0.f) * w3;
    float di1 = dinv[n1];
    float r1 = di1 * fmaxf(fmaf(di1, a1, bb), 0.f) * w3;
#pragma unroll
    for (int m = 1; m < 64; m <<= 1) {
        r0 += __shfl_xor(r0, m, 64);
        r1 += __shfl_xor(r1, m, 64);
    }
    if (lane == 0) { t3[n0] = r0; t3[n1] = r1; }
}

// Scalar last layer, 4 lanes per node (16 nodes/wave): lanes stride edges by
// 4 (4 independent loads in flight each), 2-step butterfly reduce, lane 0 of
// each group writes. t3 is 400KB (L2-resident) — pure latency-bound gather,
// so 4x the lanes ~ 4x the throughput vs 1 thread/node.
__global__ __launch_bounds__(256) void k_aggregate3(const int* __restrict__ rowptr,
                                                    const int* __restrict__ ssrc,
                                                    const float* __restrict__ t3,
                                                    const float* __restrict__ dinv,
                                                    const float* __restrict__ b3,
                                                    float* __restrict__ out) {
    int w = threadIdx.x >> 6, lane = threadIdx.x & 63;
    int grp = lane >> 2, sub = lane & 3;
    int node = blockIdx.x * 64 + w * 16 + grp;
    if (node >= NN) return;
    int s = rowptr[node], e = rowptr[node + 1];
    float acc = (sub == 0) ? t3[node] : 0.f;   // self loop once
    for (int i = s + sub; i < e; i += 4) acc += t3[ssrc[i]];
    acc += __shfl_xor(acc, 1, 64);
    acc += __shfl_xor(acc, 2, 64);
    if (sub == 0) out[node] = dinv[node] * acc + b3[0];
}

// ---------------------------------------------------------------------------
extern "C" void kernel_launch(void* const* d_in, const int* in_sizes, int n_in,
                              void* d_out, int out_size, void* d_ws, size_t ws_size,
                              hipStream_t stream) {
    const float* x  = (const float*)d_in[0];
    const void*  ei = d_in[1];
    const float* W1 = (const float*)d_in[2];
    const float* b1 = (const float*)d_in[3];
    const float* W2 = (const float*)d_in[4];
    const float* b2 = (const float*)d_in[5];
    const float* W3 = (const float*)d_in[6];
    const float* b3 = (const float*)d_in[7];
    float* out = (float*)d_out;

    char* ws = (char*)d_ws;
    size_t off_b = 0;
    auto take = [&](size_t bytes) -> char* {
        char* p = ws + off_b;
        off_b = (off_b + bytes + 255) & ~(size_t)255;
        return p;
    };
    float*    dinv   = (float*)take((size_t)NN * 4);
    int*      bsum   = (int*)take(128 * 4);
    int*      rowptr = (int*)take((size_t)(NN + 1) * 4);
    int*      hist   = (int*)take((size_t)NSC * 4);
    int*      histS  = (int*)take((size_t)NSC * 4);
    unsigned* packed = (unsigned*)take((size_t)NE * 4);
    int*      ssrc   = (int*)take((size_t)NE * 4);
    float2*   xn     = (float2*)take((size_t)NN * 8);
    __half*   tn1    = (__half*)take((size_t)NN * 64 * 2);
    float*    t3     = (float*)take((size_t)NN * 4);

    // --- atomic-free radix partition by dst (coarse buckets of 256 nodes) ---
    k_hist<<<B_P, 256, 0, stream>>>(ei, hist);
    k_gscan1<<<NBLK_H, 256, 0, stream>>>(hist, histS, bsum, NSC);
    k_gscan2<<<1, 128, 0, stream>>>(bsum, NBLK_H);
    k_part<<<B_P, 256, 0, stream>>>(ei, histS, bsum, packed);

    // --- fused per-bucket: count + scan -> rowptr/dinv/xn + place ssrc ---
    k_bucket<<<K_B, 256, 0, stream>>>(histS, bsum, packed, x, rowptr, dinv, xn, ssrc);

    // --- layer 1 + W2 (4 nodes/wave gather, in-wave 64x64 matvec, fp16 out) ---
    k_layer1<<<(NN + 15) / 16, 256, 0, stream>>>(rowptr, ssrc, xn, dinv, W1, b1, W2, tn1);

    // --- layer 2 aggregate (2 nodes/wave, unroll 8) + epilogue + W3 dot ---
    k_layer2agg<<<(NN + 7) / 8, 256, 0, stream>>>(rowptr, ssrc, tn1, dinv, b2, W3, t3);

    // --- layer 3b (4 lanes/node aggregate) ---
    k_aggregate3<<<(NN + 63) / 64, 256, 0, stream>>>(rowptr, ssrc, t3, dinv, b3, out);
}